// Round 11
// baseline (187.973 us; speedup 1.0000x reference)
//
#include <hip/hip_runtime.h>
#include <hip/hip_bf16.h>
#include <hip/hip_fp16.h>

// Problem constants
#define NB 16
#define DD 64
#define HW 4096          // 64*64
#define NTOT 65536       // NB*HW
#define KC 1024

// Output chunk offsets (FLOAT32 elements, return order)
#define O_EK   0
#define O_IDX  4194304
#define O_L    4259840
#define O_CB   4259841
#define O_CNT  4325377
#define O_SUM  4326401

// Workspace layout (float element offsets)
#define WS_IDX    0          // [0, 65536) int32
#define WS_LCPART 65536      // 512 floats
#define WS_N      66048      // scalar
#define WS_CNORM  66560      // 1024
#define WS_PSUM   67584      // 4 x 65536 -> ends 329728
#define WS_PCNT   329728     // 4 x 1024 ints -> ends 333824
#define WS_CBH    399360     // 65536 ushort = 32768 floats
#define WS_CBL    432128     // 65536 ushort = 32768 floats

#define MARGIN 0.002f

typedef _Float16 v8h __attribute__((ext_vector_type(8)));
typedef float    v4f __attribute__((ext_vector_type(4)));

// cnorm + n + codebook fp16 hi/lo split
__global__ __launch_bounds__(256) void k_pre(const float* __restrict__ cb,
                                             const float* __restrict__ ema_count,
                                             float* __restrict__ cnorm,
                                             float* __restrict__ n_ws,
                                             unsigned short* __restrict__ cbh,
                                             unsigned short* __restrict__ cbl) {
    const int t = threadIdx.x;
    const int w = (blockIdx.x * 256 + t) >> 6;   // code 0..1023 (grid 256)
    const int l = t & 63;
    float s = 0.f;
    if (l < 16) {
        float4 v = *(const float4*)(cb + (size_t)w * DD + l * 4);
        s = v.x * v.x + v.y * v.y + v.z * v.z + v.w * v.w;
    }
#pragma unroll
    for (int m = 1; m <= 8; m <<= 1) s += __shfl_xor(s, m, 64);
    if (l == 0) cnorm[w] = s;

    // fp16 hi/lo conversion: 16384 float4s
    const int e4 = blockIdx.x * 256 + t;
    if (e4 < 16384) {
        float4 v4 = ((const float4*)cb)[e4];
        __half hx = __float2half(v4.x), hy = __float2half(v4.y),
               hz = __float2half(v4.z), hw2 = __float2half(v4.w);
        ushort4 h4 = { __half_as_ushort(hx), __half_as_ushort(hy),
                       __half_as_ushort(hz), __half_as_ushort(hw2) };
        ((ushort4*)cbh)[e4] = h4;
        ushort4 l4 = { __half_as_ushort(__float2half(v4.x - __half2float(hx))),
                       __half_as_ushort(__float2half(v4.y - __half2float(hy))),
                       __half_as_ushort(__float2half(v4.z - __half2float(hz))),
                       __half_as_ushort(__float2half(v4.w - __half2float(hw2))) };
        ((ushort4*)cbl)[e4] = l4;
    }

    if (blockIdx.x == 0) {
        __shared__ float red[256];
        red[t] = ema_count[t] + ema_count[t + 256] + ema_count[t + 512] + ema_count[t + 768];
        __syncthreads();
        for (int s2 = 128; s2 >= 1; s2 >>= 1) {
            if (t < s2) red[t] += red[t + s2];
            __syncthreads();
        }
        if (t == 0) n_ws[0] = 0.99f * red[0] + 0.01f * 65536.0f;
    }
}

// Fused MFMA argmin + exact near-tie fix + e_k_ste + idx + L_commit partial.
// Block 256 = 4 waves; wave = 32 rows; 512 blocks.
__global__ __launch_bounds__(256) void k_argmin(const float* __restrict__ z_e,
                                                const float* __restrict__ cb,
                                                const unsigned short* __restrict__ cbh,
                                                const unsigned short* __restrict__ cbl,
                                                const float* __restrict__ cnorm,
                                                int* __restrict__ idx_ws,
                                                float* __restrict__ out,
                                                float* __restrict__ lc_part) {
    __shared__ __align__(16) float At[64 * 128];           // z fp32 [j][m], 32 KB, live all phases
    __shared__ __align__(16) unsigned short Bh[128 * 72];  // cb hi [code][j], 18.4 KB
    __shared__ __align__(16) unsigned short Bl[128 * 72];  // cb lo
    __shared__ __align__(16) float cn_lds[KC];             // 4 KB
    __shared__ float znl[128];
    __shared__ int   idx_lds[128];
    __shared__ int   flagrows[128];
    __shared__ int   nflag;
    __shared__ float redv[256];
    __shared__ int   redi[256];
    __shared__ float lcred[4];

    const int t  = threadIdx.x;
    const int n0 = blockIdx.x * 128;
    const int b   = n0 >> 12;
    const int hw0 = n0 & 4095;
    const float* zbase = z_e + (size_t)b * (DD * HW) + hw0;

    if (t == 0) nflag = 0;
    *(float4*)&cn_lds[t * 4] = *(const float4*)(cnorm + t * 4);

    // ---- A staging: coalesced float4 -> At[j][m] (conflict-free) ----
#pragma unroll
    for (int s = 0; s < 8; ++s) {
        int idx = t + s * 256;              // 0..2047 float4s
        int j   = idx >> 5;
        int i4  = (idx & 31) << 2;
        float4 v = *(const float4*)(zbase + (size_t)j * HW + i4);
        *(float4*)(&At[j * 128 + i4]) = v;
    }
    __syncthreads();

    // exact fp32 zn chain (j ascending), row t
    if (t < 128) {
        float s = 0.f;
        for (int j = 0; j < 64; ++j) { float a = At[j * 128 + t]; s = fmaf(a, a, s); }
        znl[t] = s;
    }
    __syncthreads();

    const int w    = t >> 6;        // wave 0..3 -> rows [32w, 32w+32)
    const int lane = t & 63;
    const int c    = lane & 15;     // col within 16-tile / A-row m
    const int q    = lane >> 4;     // k-quad

    // ---- A fragments built once from At (hi/lo fp16 split, RTNE as before) ----
    v8h Afh[2][2], Afl[2][2];
#pragma unroll
    for (int g = 0; g < 2; ++g) {
        int m = 32 * w + 16 * g + c;
#pragma unroll
        for (int s = 0; s < 2; ++s) {
            v8h hi, lo;
#pragma unroll
            for (int jj = 0; jj < 8; ++jj) {
                float v = At[(s * 32 + q * 8 + jj) * 128 + m];
                _Float16 h = (_Float16)v;
                hi[jj] = h;
                lo[jj] = (_Float16)(v - (float)h);
            }
            Afh[g][s] = hi; Afl[g][s] = lo;
        }
    }

    float m1v[2][4], m2v[2][4]; int m1i[2][4];
#pragma unroll
    for (int g = 0; g < 2; ++g)
#pragma unroll
        for (int r = 0; r < 4; ++r) { m1v[g][r] = 3.4e38f; m2v[g][r] = 3.4e38f; m1i[g][r] = 0; }

    for (int kt = 0; kt < 8; ++kt) {
        __syncthreads();
        // stage 128 codes (hi+lo) from global fp16 arrays (L2-hot)
#pragma unroll
        for (int s2 = 0; s2 < 4; ++s2) {
            int idx = t + s2 * 256;               // 0..1023
            int code = idx >> 3;
            int off  = (idx & 7) * 8;
            size_t gsrc = ((size_t)(kt * 128 + code)) * 64 + off;
            *(uint4*)&Bh[code * 72 + off] = *(const uint4*)(cbh + gsrc);
            *(uint4*)&Bl[code * 72 + off] = *(const uint4*)(cbl + gsrc);
        }
        __syncthreads();

#pragma unroll
        for (int sub = 0; sub < 8; ++sub) {
            const int cl = sub * 16 + c;
            v8h Bfh0 = *(const v8h*)&Bh[cl * 72 + q * 8];
            v8h Bfh1 = *(const v8h*)&Bh[cl * 72 + 32 + q * 8];
            v8h Bfl0 = *(const v8h*)&Bl[cl * 72 + q * 8];
            v8h Bfl1 = *(const v8h*)&Bl[cl * 72 + 32 + q * 8];
            float cnc = cn_lds[kt * 128 + cl];
            const int kg = kt * 128 + cl;
#pragma unroll
            for (int g = 0; g < 2; ++g) {
                v4f acc = {0.f, 0.f, 0.f, 0.f};
                acc = __builtin_amdgcn_mfma_f32_16x16x32_f16(Afh[g][0], Bfh0, acc, 0, 0, 0);
                acc = __builtin_amdgcn_mfma_f32_16x16x32_f16(Afh[g][1], Bfh1, acc, 0, 0, 0);
                acc = __builtin_amdgcn_mfma_f32_16x16x32_f16(Afh[g][0], Bfl0, acc, 0, 0, 0);
                acc = __builtin_amdgcn_mfma_f32_16x16x32_f16(Afh[g][1], Bfl1, acc, 0, 0, 0);
                acc = __builtin_amdgcn_mfma_f32_16x16x32_f16(Afl[g][0], Bfh0, acc, 0, 0, 0);
                acc = __builtin_amdgcn_mfma_f32_16x16x32_f16(Afl[g][1], Bfh1, acc, 0, 0, 0);
#pragma unroll
                for (int r = 0; r < 4; ++r) {
                    float v = fmaf(-2.0f, acc[r], cnc);   // zn omitted: per-row constant
                    bool better = v < m1v[g][r];          // strict: kg ascending keeps first
                    m2v[g][r] = better ? m1v[g][r] : fminf(m2v[g][r], v);
                    m1i[g][r] = better ? kg : m1i[g][r];
                    m1v[g][r] = better ? v : m1v[g][r];
                }
            }
        }
    }

    // ---- top-2 merge across the 16 lanes holding each row ----
#pragma unroll
    for (int g = 0; g < 2; ++g)
#pragma unroll
        for (int r = 0; r < 4; ++r) {
            float a = m1v[g][r], b2 = m2v[g][r]; int ii = m1i[g][r];
#pragma unroll
            for (int mask = 1; mask <= 8; mask <<= 1) {
                float ov = __shfl_xor(a, mask, 64);
                int   oi = __shfl_xor(ii, mask, 64);
                float o2 = __shfl_xor(b2, mask, 64);
                bool take = (ov < a) || (ov == a && oi < ii);
                float loser = take ? a : ov;
                b2 = fminf(fminf(b2, o2), loser);
                a  = take ? ov : a;
                ii = take ? oi : ii;
            }
            if (c == 0) {
                int row = 32 * w + 16 * g + q * 4 + r;
                idx_lds[row] = ii;
                if ((b2 - a) < MARGIN) { int p = atomicAdd(&nflag, 1); flagrows[p] = row; }
            }
        }
    __syncthreads();

    // ---- exact fp32 fix for flagged rows (np-matching expressions) ----
    const int nf = nflag;
    for (int f = 0; f < nf; ++f) {
        int row = flagrows[f];
        float znr = znl[row];
        float best = 3.4e38f; int bi = 0;
#pragma unroll
        for (int c2 = 0; c2 < 4; ++c2) {
            int k = t * 4 + c2;                      // ascending within thread
            const float* ck = cb + (size_t)k * DD;
            float acc = 0.f;
            for (int j = 0; j < 64; ++j) acc = fmaf(At[j * 128 + row], ck[j], acc);
            float v = (znr - 2.0f * acc) + cn_lds[k];
            if (v < best) { best = v; bi = k; }
        }
        redv[t] = best; redi[t] = bi;
        __syncthreads();
        for (int s = 128; s >= 1; s >>= 1) {
            if (t < s) {
                float v = redv[t + s]; int i = redi[t + s];
                if (v < redv[t] || (v == redv[t] && i < redi[t])) { redv[t] = v; redi[t] = i; }
            }
            __syncthreads();
        }
        if (t == 0) idx_lds[row] = redi[0];
        __syncthreads();
    }

    if (t < 128) {
        int bi = idx_lds[t];
        out[O_IDX + n0 + t] = (float)bi;
        idx_ws[n0 + t] = bi;
    }
    __syncthreads();

    // ---- e_k_ste + L_commit from At ----
    const int r  = t >> 1;
    const int j0 = (t & 1) * 32;
    int k = idx_lds[r];
    const float* ck = cb + (size_t)k * DD;
    const size_t obase = (size_t)b * (DD * HW) + (size_t)(hw0 + r);

    float lc = 0.f;
#pragma unroll 8
    for (int j = j0; j < j0 + 32; ++j) {
        float z = At[j * 128 + r];
        float e = ck[j];
        out[O_EK + obase + (size_t)j * HW] = z + (e - z);
        float d = z - e;
        lc = fmaf(d, d, lc);
    }
#pragma unroll
    for (int m = 32; m >= 1; m >>= 1) lc += __shfl_xor(lc, m, 64);
    if ((t & 63) == 0) lcred[t >> 6] = lc;
    __syncthreads();
    if (t == 0) lc_part[blockIdx.x] = lcred[0] + lcred[1] + lcred[2] + lcred[3];
}

// 256 blocks: (j, chunk c). Vectorized loads; LDS accumulate; j==0 also histograms.
__global__ __launch_bounds__(1024) void k_sums(const int* __restrict__ idx_ws,
                                               const float* __restrict__ z_e,
                                               float* __restrict__ psum,
                                               int* __restrict__ pcnt) {
    __shared__ float acc[KC];
    __shared__ int bins[KC];
    const int j = blockIdx.x & 63;
    const int c = blockIdx.x >> 6;
    const int t = threadIdx.x;
    acc[t] = 0.f;
    bins[t] = 0;
    __syncthreads();
    const float* zj = z_e + (size_t)j * HW;
    const int base = c * 16384;
    if (j == 0) {
#pragma unroll
        for (int i = 0; i < 4; ++i) {
            int n4 = base + i * 4096 + t * 4;
            int b = n4 >> 12, hw = n4 & 4095;
            float4 z4 = *(const float4*)(zj + (size_t)b * (DD * HW) + hw);
            int4   k4 = *(const int4*)(idx_ws + n4);
            atomicAdd(&acc[k4.x], z4.x); atomicAdd(&bins[k4.x], 1);
            atomicAdd(&acc[k4.y], z4.y); atomicAdd(&bins[k4.y], 1);
            atomicAdd(&acc[k4.z], z4.z); atomicAdd(&bins[k4.z], 1);
            atomicAdd(&acc[k4.w], z4.w); atomicAdd(&bins[k4.w], 1);
        }
    } else {
#pragma unroll
        for (int i = 0; i < 4; ++i) {
            int n4 = base + i * 4096 + t * 4;
            int b = n4 >> 12, hw = n4 & 4095;
            float4 z4 = *(const float4*)(zj + (size_t)b * (DD * HW) + hw);
            int4   k4 = *(const int4*)(idx_ws + n4);
            atomicAdd(&acc[k4.x], z4.x);
            atomicAdd(&acc[k4.y], z4.y);
            atomicAdd(&acc[k4.z], z4.z);
            atomicAdd(&acc[k4.w], z4.w);
        }
    }
    __syncthreads();
    psum[(size_t)c * 65536 + j * 1024 + t] = acc[t];
    if (j == 0) pcnt[c * 1024 + t] = bins[t];
}

// Fused epilogue, coalesced on outputs: e = k*64+j. 64 blocks x 1024.
__global__ __launch_bounds__(1024) void k_epi(const float* __restrict__ psum,
                                              const int* __restrict__ pcnt,
                                              const float* __restrict__ ema_sum,
                                              const float* __restrict__ ema_count,
                                              const float* __restrict__ n_ws,
                                              const float* __restrict__ lc_part,
                                              float* __restrict__ out) {
    const int t = threadIdx.x;
    const int e = blockIdx.x * 1024 + t;
    const int k = e >> 6, j = e & 63;
    float s4 = psum[j * 1024 + k] + psum[65536 + j * 1024 + k]
             + psum[131072 + j * 1024 + k] + psum[196608 + j * 1024 + k];
    float ns = ema_sum[e] * 0.99f + 0.01f * s4;
    out[O_SUM + e] = ns;
    int cnt = pcnt[k] + pcnt[1024 + k] + pcnt[2048 + k] + pcnt[3072 + k];
    float nc = ema_count[k] * 0.99f + 0.01f * (float)cnt;
    float n  = n_ws[0];
    float cs = (nc + 1e-5f) / (n + 1024.0f * 1e-5f) * n;
    out[O_CB + e] = ns / cs;
    if (blockIdx.x == 0) {
        int c2 = pcnt[t] + pcnt[1024 + t] + pcnt[2048 + t] + pcnt[3072 + t];
        out[O_CNT + t] = ema_count[t] * 0.99f + 0.01f * (float)c2;
    }
    if (blockIdx.x == 1) {
        __shared__ float red[512];
        if (t < 512) red[t] = lc_part[t];
        __syncthreads();
        for (int s = 256; s >= 1; s >>= 1) {
            if (t < s) red[t] += red[t + s];
            __syncthreads();
        }
        if (t == 0) out[O_L] = 1.25f * red[0] * (1.0f / 4194304.0f);
    }
}

extern "C" void kernel_launch(void* const* d_in, const int* in_sizes, int n_in,
                              void* d_out, int out_size, void* d_ws, size_t ws_size,
                              hipStream_t stream) {
    const float* z_e       = (const float*)d_in[0];
    const float* cb        = (const float*)d_in[1];
    const float* ema_count = (const float*)d_in[2];
    const float* ema_sum   = (const float*)d_in[3];
    float* out             = (float*)d_out;

    float* ws_f      = (float*)d_ws;
    int*   idx_ws    = (int*)d_ws;
    float* lc_part   = ws_f + WS_LCPART;
    float* n_ws      = ws_f + WS_N;
    float* cnorm_ws  = ws_f + WS_CNORM;
    float* psum      = ws_f + WS_PSUM;
    int*   pcnt      = (int*)(ws_f + WS_PCNT);
    unsigned short* cbh = (unsigned short*)(ws_f + WS_CBH);
    unsigned short* cbl = (unsigned short*)(ws_f + WS_CBL);

    k_pre<<<256, 256, 0, stream>>>(cb, ema_count, cnorm_ws, n_ws, cbh, cbl);
    k_argmin<<<NTOT / 128, 256, 0, stream>>>(z_e, cb, cbh, cbl, cnorm_ws, idx_ws, out, lc_part);
    k_sums<<<256, 1024, 0, stream>>>(idx_ws, z_e, psum, pcnt);
    k_epi<<<64, 1024, 0, stream>>>(psum, pcnt, ema_sum, ema_count, n_ws, lc_part, out);
}

// Round 12
// 164.475 us; speedup vs baseline: 1.1429x; 1.1429x over previous
//
#include <hip/hip_runtime.h>
#include <hip/hip_bf16.h>
#include <hip/hip_fp16.h>

// Problem constants
#define NB 16
#define DD 64
#define HW 4096          // 64*64
#define NTOT 65536       // NB*HW
#define KC 1024

// Output chunk offsets (FLOAT32 elements, return order)
#define O_EK   0
#define O_IDX  4194304
#define O_L    4259840
#define O_CB   4259841
#define O_CNT  4325377
#define O_SUM  4326401

// Workspace layout (float element offsets)
#define WS_IDX    0          // [0, 65536) int32
#define WS_LCPART 65536      // 256 floats used
#define WS_N      66048      // scalar
#define WS_CNORM  66560      // 1024
#define WS_PSUM   67584      // 4 x 65536 -> ends 329728
#define WS_PCNT   329728     // 4 x 1024 ints -> ends 333824
#define WS_CBH    399360     // 65536 ushort
#define WS_CBL    432128     // 65536 ushort

#define MARGIN 0.002f

typedef _Float16 v8h __attribute__((ext_vector_type(8)));
typedef float    v4f __attribute__((ext_vector_type(4)));

// cnorm + n + codebook fp16 hi/lo split
__global__ __launch_bounds__(256) void k_pre(const float* __restrict__ cb,
                                             const float* __restrict__ ema_count,
                                             float* __restrict__ cnorm,
                                             float* __restrict__ n_ws,
                                             unsigned short* __restrict__ cbh,
                                             unsigned short* __restrict__ cbl) {
    const int t = threadIdx.x;
    const int w = (blockIdx.x * 256 + t) >> 6;   // code 0..1023 (grid 256)
    const int l = t & 63;
    float s = 0.f;
    if (l < 16) {
        float4 v = *(const float4*)(cb + (size_t)w * DD + l * 4);
        s = v.x * v.x + v.y * v.y + v.z * v.z + v.w * v.w;
    }
#pragma unroll
    for (int m = 1; m <= 8; m <<= 1) s += __shfl_xor(s, m, 64);
    if (l == 0) cnorm[w] = s;

    // fp16 hi/lo conversion: 16384 float4s
    const int e4 = blockIdx.x * 256 + t;
    if (e4 < 16384) {
        float4 v4 = ((const float4*)cb)[e4];
        __half hx = __float2half(v4.x), hy = __float2half(v4.y),
               hz = __float2half(v4.z), hw2 = __float2half(v4.w);
        ushort4 h4 = { __half_as_ushort(hx), __half_as_ushort(hy),
                       __half_as_ushort(hz), __half_as_ushort(hw2) };
        ((ushort4*)cbh)[e4] = h4;
        ushort4 l4 = { __half_as_ushort(__float2half(v4.x - __half2float(hx))),
                       __half_as_ushort(__float2half(v4.y - __half2float(hy))),
                       __half_as_ushort(__float2half(v4.z - __half2float(hz))),
                       __half_as_ushort(__float2half(v4.w - __half2float(hw2))) };
        ((ushort4*)cbl)[e4] = l4;
    }

    if (blockIdx.x == 0) {
        __shared__ float red[256];
        red[t] = ema_count[t] + ema_count[t + 256] + ema_count[t + 512] + ema_count[t + 768];
        __syncthreads();
        for (int s2 = 128; s2 >= 1; s2 >>= 1) {
            if (t < s2) red[t] += red[t + s2];
            __syncthreads();
        }
        if (t == 0) n_ws[0] = 0.99f * red[0] + 0.01f * 65536.0f;
    }
}

// MFMA argmin (round-10 structure) + in-kernel exact near-tie fix + idx writes.
// Block 256 = 4 waves; wave = 32 rows; 512 blocks.
__global__ __launch_bounds__(256) void k_argmin(const float* __restrict__ z_e,
                                                const float* __restrict__ cb,
                                                const unsigned short* __restrict__ cbh,
                                                const unsigned short* __restrict__ cbl,
                                                const float* __restrict__ cnorm,
                                                int* __restrict__ idx_ws,
                                                float* __restrict__ out) {
    __shared__ __align__(16) unsigned short Ah[128 * 72];  // z hi [m][j]
    __shared__ __align__(16) unsigned short Al[128 * 72];  // z lo
    __shared__ __align__(16) unsigned short Bh[128 * 72];  // cb hi [code][j]
    __shared__ __align__(16) unsigned short Bl[128 * 72];  // cb lo
    __shared__ __align__(16) float cn_lds[KC];
    __shared__ float znl[128];
    __shared__ int   idx_lds[128];
    __shared__ int   flagrows[128];
    __shared__ int   nflag;
    __shared__ float redv4[4];
    __shared__ int   redi4[4];

    const int t  = threadIdx.x;
    const int n0 = blockIdx.x * 128;
    const int b   = n0 >> 12;
    const int hw0 = n0 & 4095;

    if (t == 0) nflag = 0;
    *(float4*)&cn_lds[t * 4] = *(const float4*)(cnorm + t * 4);

    // ---- A staging: t<128 handles row m=t; exact fp32 zn chain alongside ----
    if (t < 128) {
        const float* zp = z_e + (size_t)b * (DD * HW) + hw0 + t;
        float s = 0.f;
        unsigned ph = 0, pl = 0;
        for (int j = 0; j < 64; ++j) {
            float v = zp[(size_t)j * HW];               // coalesced across lanes
            s = fmaf(v, v, s);                          // exact zn chain (j ascending)
            __half h = __float2half(v);
            float hf = __half2float(h);
            __half lo = __float2half(v - hf);
            unsigned uh = __half_as_ushort(h), ul = __half_as_ushort(lo);
            if ((j & 1) == 0) { ph = uh; pl = ul; }
            else {
                *(unsigned*)&Ah[t * 72 + j - 1] = ph | (uh << 16);
                *(unsigned*)&Al[t * 72 + j - 1] = pl | (ul << 16);
            }
        }
        znl[t] = s;
    }
    __syncthreads();

    const int w    = t >> 6;        // wave 0..3 -> rows [32w, 32w+32)
    const int lane = t & 63;
    const int c    = lane & 15;     // col within 16-tile
    const int q    = lane >> 4;     // k-quad / row-quad

    // A fragments, loaded once: [group g][K-step s]
    v8h Afh[2][2], Afl[2][2];
#pragma unroll
    for (int g = 0; g < 2; ++g) {
        int m = 32 * w + 16 * g + c;
#pragma unroll
        for (int s = 0; s < 2; ++s) {
            Afh[g][s] = *(const v8h*)&Ah[m * 72 + s * 32 + q * 8];
            Afl[g][s] = *(const v8h*)&Al[m * 72 + s * 32 + q * 8];
        }
    }

    float m1v[2][4], m2v[2][4]; int m1i[2][4];
#pragma unroll
    for (int g = 0; g < 2; ++g)
#pragma unroll
        for (int r = 0; r < 4; ++r) { m1v[g][r] = 3.4e38f; m2v[g][r] = 3.4e38f; m1i[g][r] = 0; }

    for (int kt = 0; kt < 8; ++kt) {
        __syncthreads();
        // stage 128 codes (hi+lo) from global fp16 arrays
#pragma unroll
        for (int s2 = 0; s2 < 4; ++s2) {
            int idx = t + s2 * 256;               // 0..1023
            int code = idx >> 3;
            int off  = (idx & 7) * 8;
            size_t gsrc = ((size_t)(kt * 128 + code)) * 64 + off;
            *(uint4*)&Bh[code * 72 + off] = *(const uint4*)(cbh + gsrc);
            *(uint4*)&Bl[code * 72 + off] = *(const uint4*)(cbl + gsrc);
        }
        __syncthreads();

#pragma unroll
        for (int sub = 0; sub < 8; ++sub) {
            const int cl = sub * 16 + c;
            v8h Bfh0 = *(const v8h*)&Bh[cl * 72 + q * 8];
            v8h Bfh1 = *(const v8h*)&Bh[cl * 72 + 32 + q * 8];
            v8h Bfl0 = *(const v8h*)&Bl[cl * 72 + q * 8];
            v8h Bfl1 = *(const v8h*)&Bl[cl * 72 + 32 + q * 8];
            float cnc = cn_lds[kt * 128 + cl];
            const int kg = kt * 128 + cl;
#pragma unroll
            for (int g = 0; g < 2; ++g) {
                v4f acc = {0.f, 0.f, 0.f, 0.f};
                acc = __builtin_amdgcn_mfma_f32_16x16x32_f16(Afh[g][0], Bfh0, acc, 0, 0, 0);
                acc = __builtin_amdgcn_mfma_f32_16x16x32_f16(Afh[g][1], Bfh1, acc, 0, 0, 0);
                acc = __builtin_amdgcn_mfma_f32_16x16x32_f16(Afh[g][0], Bfl0, acc, 0, 0, 0);
                acc = __builtin_amdgcn_mfma_f32_16x16x32_f16(Afh[g][1], Bfl1, acc, 0, 0, 0);
                acc = __builtin_amdgcn_mfma_f32_16x16x32_f16(Afl[g][0], Bfh0, acc, 0, 0, 0);
                acc = __builtin_amdgcn_mfma_f32_16x16x32_f16(Afl[g][1], Bfh1, acc, 0, 0, 0);
#pragma unroll
                for (int r = 0; r < 4; ++r) {
                    float v = fmaf(-2.0f, acc[r], cnc);   // zn omitted: per-row constant
                    bool better = v < m1v[g][r];          // strict: kg ascending keeps first
                    m2v[g][r] = better ? m1v[g][r] : fminf(m2v[g][r], v);
                    m1i[g][r] = better ? kg : m1i[g][r];
                    m1v[g][r] = better ? v : m1v[g][r];
                }
            }
        }
    }

    // ---- top-2 merge across the 16 lanes holding each row ----
#pragma unroll
    for (int g = 0; g < 2; ++g)
#pragma unroll
        for (int r = 0; r < 4; ++r) {
            float a = m1v[g][r], b2 = m2v[g][r]; int ii = m1i[g][r];
#pragma unroll
            for (int mask = 1; mask <= 8; mask <<= 1) {
                float ov = __shfl_xor(a, mask, 64);
                int   oi = __shfl_xor(ii, mask, 64);
                float o2 = __shfl_xor(b2, mask, 64);
                bool take = (ov < a) || (ov == a && oi < ii);
                float loser = take ? a : ov;
                b2 = fminf(fminf(b2, o2), loser);
                a  = take ? ov : a;
                ii = take ? oi : ii;
            }
            if (c == 0) {
                int row = 32 * w + 16 * g + q * 4 + r;
                idx_lds[row] = ii;
                if ((b2 - a) < MARGIN) { int p = atomicAdd(&nflag, 1); flagrows[p] = row; }
            }
        }
    __syncthreads();

    // ---- exact fp32 fix for flagged rows (rare; np-matching expressions) ----
    const int nf = nflag;
    for (int f = 0; f < nf; ++f) {
        int row = flagrows[f];
        const float* zrow = z_e + (size_t)b * (DD * HW) + hw0 + row;
        float znr = znl[row];
        float best = 3.4e38f; int bi = 0;
#pragma unroll
        for (int c2 = 0; c2 < 4; ++c2) {
            int k = t * 4 + c2;                      // ascending within thread
            const float* ck = cb + (size_t)k * DD;
            float acc = 0.f;
            for (int j = 0; j < 64; ++j) acc = fmaf(zrow[(size_t)j * HW], ck[j], acc);
            float v = (znr - 2.0f * acc) + cn_lds[k];
            if (v < best) { best = v; bi = k; }
        }
        // wave reduce (64 lanes) with first-index tie rule
#pragma unroll
        for (int mask = 1; mask <= 32; mask <<= 1) {
            float ov = __shfl_xor(best, mask, 64);
            int   oi = __shfl_xor(bi, mask, 64);
            if (ov < best || (ov == best && oi < bi)) { best = ov; bi = oi; }
        }
        if (lane == 0) { redv4[w] = best; redi4[w] = bi; }
        __syncthreads();
        if (t == 0) {
            float bv = redv4[0]; int bix = redi4[0];
#pragma unroll
            for (int w2 = 1; w2 < 4; ++w2) {
                if (redv4[w2] < bv || (redv4[w2] == bv && redi4[w2] < bix)) { bv = redv4[w2]; bix = redi4[w2]; }
            }
            idx_lds[row] = bix;
        }
        __syncthreads();
    }

    if (t < 128) {
        int bi = idx_lds[t];
        out[O_IDX + n0 + t] = (float)bi;
        idx_ws[n0 + t] = bi;
    }
}

// Fused output pass: 256 blocks (j, chunk c). Reads z once: e_k_ste + segment sums
// + histogram (j==0) + L_commit partials. cb column j staged in LDS.
__global__ __launch_bounds__(1024) void k_out(const int* __restrict__ idx_ws,
                                              const float* __restrict__ z_e,
                                              const float* __restrict__ cb,
                                              float* __restrict__ psum,
                                              int* __restrict__ pcnt,
                                              float* __restrict__ lc_part,
                                              float* __restrict__ out) {
    __shared__ float acc[KC];
    __shared__ int bins[KC];
    __shared__ float cbj[KC];
    __shared__ float lcr[16];
    const int j = blockIdx.x & 63;
    const int c = blockIdx.x >> 6;
    const int t = threadIdx.x;
    acc[t] = 0.f;
    bins[t] = 0;
    cbj[t] = cb[(size_t)t * DD + j];   // codebook column j (stride-256B, once per block)
    __syncthreads();
    const float* zj = z_e + (size_t)j * HW;
    float* oj = out + O_EK + (size_t)j * HW;
    const int base = c * 16384;
    float lc = 0.f;
#pragma unroll
    for (int i = 0; i < 4; ++i) {
        int n4 = base + i * 4096 + t * 4;
        int b = n4 >> 12, hw = n4 & 4095;
        size_t zoff = (size_t)b * (DD * HW) + hw;
        float4 z4 = *(const float4*)(zj + zoff);
        int4   k4 = *(const int4*)(idx_ws + n4);
        float e0 = cbj[k4.x], e1 = cbj[k4.y], e2 = cbj[k4.z], e3 = cbj[k4.w];
        float4 o4 = { z4.x + (e0 - z4.x), z4.y + (e1 - z4.y),
                      z4.z + (e2 - z4.z), z4.w + (e3 - z4.w) };
        *(float4*)(oj + zoff) = o4;                       // coalesced
        float d0 = z4.x - e0, d1 = z4.y - e1, d2 = z4.z - e2, d3 = z4.w - e3;
        lc = fmaf(d0, d0, lc); lc = fmaf(d1, d1, lc);
        lc = fmaf(d2, d2, lc); lc = fmaf(d3, d3, lc);
        atomicAdd(&acc[k4.x], z4.x);
        atomicAdd(&acc[k4.y], z4.y);
        atomicAdd(&acc[k4.z], z4.z);
        atomicAdd(&acc[k4.w], z4.w);
        if (j == 0) {
            atomicAdd(&bins[k4.x], 1); atomicAdd(&bins[k4.y], 1);
            atomicAdd(&bins[k4.z], 1); atomicAdd(&bins[k4.w], 1);
        }
    }
    __syncthreads();
    psum[(size_t)c * 65536 + j * 1024 + t] = acc[t];
    if (j == 0) pcnt[c * 1024 + t] = bins[t];
    // L_commit partial
#pragma unroll
    for (int m = 32; m >= 1; m >>= 1) lc += __shfl_xor(lc, m, 64);
    if ((t & 63) == 0) lcr[t >> 6] = lc;
    __syncthreads();
    if (t == 0) {
        float s = 0.f;
#pragma unroll
        for (int u = 0; u < 16; ++u) s += lcr[u];
        lc_part[blockIdx.x] = s;
    }
}

// Fused epilogue, coalesced on outputs: e = k*64+j. 64 blocks x 1024.
__global__ __launch_bounds__(1024) void k_epi(const float* __restrict__ psum,
                                              const int* __restrict__ pcnt,
                                              const float* __restrict__ ema_sum,
                                              const float* __restrict__ ema_count,
                                              const float* __restrict__ n_ws,
                                              const float* __restrict__ lc_part,
                                              float* __restrict__ out) {
    const int t = threadIdx.x;
    const int e = blockIdx.x * 1024 + t;
    const int k = e >> 6, j = e & 63;
    float s4 = psum[j * 1024 + k] + psum[65536 + j * 1024 + k]
             + psum[131072 + j * 1024 + k] + psum[196608 + j * 1024 + k];
    float ns = ema_sum[e] * 0.99f + 0.01f * s4;
    out[O_SUM + e] = ns;
    int cnt = pcnt[k] + pcnt[1024 + k] + pcnt[2048 + k] + pcnt[3072 + k];
    float nc = ema_count[k] * 0.99f + 0.01f * (float)cnt;
    float n  = n_ws[0];
    float cs = (nc + 1e-5f) / (n + 1024.0f * 1e-5f) * n;
    out[O_CB + e] = ns / cs;
    if (blockIdx.x == 0) {
        int c2 = pcnt[t] + pcnt[1024 + t] + pcnt[2048 + t] + pcnt[3072 + t];
        out[O_CNT + t] = ema_count[t] * 0.99f + 0.01f * (float)c2;
    }
    if (blockIdx.x == 1) {
        __shared__ float red[512];
        if (t < 512) red[t] = (t < 256) ? lc_part[t] : 0.f;
        __syncthreads();
        for (int s = 256; s >= 1; s >>= 1) {
            if (t < s) red[t] += red[t + s];
            __syncthreads();
        }
        if (t == 0) out[O_L] = 1.25f * red[0] * (1.0f / 4194304.0f);
    }
}

extern "C" void kernel_launch(void* const* d_in, const int* in_sizes, int n_in,
                              void* d_out, int out_size, void* d_ws, size_t ws_size,
                              hipStream_t stream) {
    const float* z_e       = (const float*)d_in[0];
    const float* cb        = (const float*)d_in[1];
    const float* ema_count = (const float*)d_in[2];
    const float* ema_sum   = (const float*)d_in[3];
    float* out             = (float*)d_out;

    float* ws_f      = (float*)d_ws;
    int*   idx_ws    = (int*)d_ws;
    float* lc_part   = ws_f + WS_LCPART;
    float* n_ws      = ws_f + WS_N;
    float* cnorm_ws  = ws_f + WS_CNORM;
    float* psum      = ws_f + WS_PSUM;
    int*   pcnt      = (int*)(ws_f + WS_PCNT);
    unsigned short* cbh = (unsigned short*)(ws_f + WS_CBH);
    unsigned short* cbl = (unsigned short*)(ws_f + WS_CBL);

    k_pre<<<256, 256, 0, stream>>>(cb, ema_count, cnorm_ws, n_ws, cbh, cbl);
    k_argmin<<<NTOT / 128, 256, 0, stream>>>(z_e, cb, cbh, cbl, cnorm_ws, idx_ws, out);
    k_out<<<256, 1024, 0, stream>>>(idx_ws, z_e, cb, psum, pcnt, lc_part, out);
    k_epi<<<64, 1024, 0, stream>>>(psum, pcnt, ema_sum, ema_count, n_ws, lc_part, out);
}

// Round 13
// 160.126 us; speedup vs baseline: 1.1739x; 1.0272x over previous
//
#include <hip/hip_runtime.h>
#include <hip/hip_bf16.h>
#include <hip/hip_fp16.h>

// Problem constants
#define NB 16
#define DD 64
#define HW 4096          // 64*64
#define NTOT 65536       // NB*HW
#define KC 1024

// Output chunk offsets (FLOAT32 elements, return order)
#define O_EK   0
#define O_IDX  4194304
#define O_L    4259840
#define O_CB   4259841
#define O_CNT  4325377
#define O_SUM  4326401

// Workspace layout (float element offsets)
#define WS_IDX    0          // [0, 65536) int32
#define WS_LCPART 65536      // 256 floats used
#define WS_N      66048      // scalar
#define WS_CNORM  66560      // 1024
#define WS_PSUM   67584      // 4 x 65536 -> ends 329728
#define WS_PCNT   329728     // 4 x 1024 ints -> ends 333824
#define WS_FLGC   333824     // 512 ints -> ends 334336
#define WS_FLGL   334336     // 512 x 32 ints -> ends 350720
#define WS_CBH    399360     // 65536 ushort
#define WS_CBL    432128     // 65536 ushort

#define MARGIN 0.002f
#define MAXFLG 32

typedef _Float16 v8h __attribute__((ext_vector_type(8)));
typedef float    v4f __attribute__((ext_vector_type(4)));

// cnorm + n + codebook fp16 hi/lo split
__global__ __launch_bounds__(256) void k_pre(const float* __restrict__ cb,
                                             const float* __restrict__ ema_count,
                                             float* __restrict__ cnorm,
                                             float* __restrict__ n_ws,
                                             unsigned short* __restrict__ cbh,
                                             unsigned short* __restrict__ cbl) {
    const int t = threadIdx.x;
    const int w = (blockIdx.x * 256 + t) >> 6;   // code 0..1023 (grid 256)
    const int l = t & 63;
    float s = 0.f;
    if (l < 16) {
        float4 v = *(const float4*)(cb + (size_t)w * DD + l * 4);
        s = v.x * v.x + v.y * v.y + v.z * v.z + v.w * v.w;
    }
#pragma unroll
    for (int m = 1; m <= 8; m <<= 1) s += __shfl_xor(s, m, 64);
    if (l == 0) cnorm[w] = s;

    // fp16 hi/lo conversion: 16384 float4s
    const int e4 = blockIdx.x * 256 + t;
    if (e4 < 16384) {
        float4 v4 = ((const float4*)cb)[e4];
        __half hx = __float2half(v4.x), hy = __float2half(v4.y),
               hz = __float2half(v4.z), hw2 = __float2half(v4.w);
        ushort4 h4 = { __half_as_ushort(hx), __half_as_ushort(hy),
                       __half_as_ushort(hz), __half_as_ushort(hw2) };
        ((ushort4*)cbh)[e4] = h4;
        ushort4 l4 = { __half_as_ushort(__float2half(v4.x - __half2float(hx))),
                       __half_as_ushort(__float2half(v4.y - __half2float(hy))),
                       __half_as_ushort(__float2half(v4.z - __half2float(hz))),
                       __half_as_ushort(__float2half(v4.w - __half2float(hw2))) };
        ((ushort4*)cbl)[e4] = l4;
    }

    if (blockIdx.x == 0) {
        __shared__ float red[256];
        red[t] = ema_count[t] + ema_count[t + 256] + ema_count[t + 512] + ema_count[t + 768];
        __syncthreads();
        for (int s2 = 128; s2 >= 1; s2 >>= 1) {
            if (t < s2) red[t] += red[t + s2];
            __syncthreads();
        }
        if (t == 0) n_ws[0] = 0.99f * red[0] + 0.01f * 65536.0f;
    }
}

// MFMA argmin with coalesced A-staging; flags exported for k_fix.
// Block 256 = 4 waves; wave = 32 rows; 512 blocks.
__global__ __launch_bounds__(256) void k_argmin(const float* __restrict__ z_e,
                                                const unsigned short* __restrict__ cbh,
                                                const unsigned short* __restrict__ cbl,
                                                const float* __restrict__ cnorm,
                                                int* __restrict__ idx_ws,
                                                int* __restrict__ flg_cnt,
                                                int* __restrict__ flg_list,
                                                float* __restrict__ out) {
    __shared__ __align__(16) unsigned short Ah[128 * 72];  // z hi [m][j]
    __shared__ __align__(16) unsigned short Al[128 * 72];  // z lo
    __shared__ __align__(16) unsigned short Bs[2][128 * 72]; // Bh/Bl; fp32 A-scratch pre-loop
    __shared__ __align__(16) float cn_lds[KC];
    __shared__ float znl[128];
    __shared__ int   idx_lds[128];
    __shared__ int   flagrows[128];
    __shared__ int   nflag;

    unsigned short* Bh = &Bs[0][0];
    unsigned short* Bl = &Bs[1][0];
    float* Atf = (float*)&Bs[0][0];       // 8192 floats fit in 9216

    const int t  = threadIdx.x;
    const int n0 = blockIdx.x * 128;
    const int b   = n0 >> 12;
    const int hw0 = n0 & 4095;
    const float* zbase = z_e + (size_t)b * (DD * HW) + hw0;

    if (t == 0) nflag = 0;
    *(float4*)&cn_lds[t * 4] = *(const float4*)(cnorm + t * 4);

    // ---- A staging phase 1: coalesced float4 -> Atf[j][m] (conflict-free) ----
#pragma unroll
    for (int s = 0; s < 8; ++s) {
        int idx = t + s * 256;              // 0..2047 float4s
        int j   = idx >> 5;
        int i4  = (idx & 31) << 2;
        float4 v = *(const float4*)(zbase + (size_t)j * HW + i4);
        *(float4*)(&Atf[j * 128 + i4]) = v;
    }
    __syncthreads();

    // ---- phase 2: LDS->LDS fp16 hi/lo conversion (all 256 threads) ----
    {
        const int m  = t & 127;
        const int j0 = (t >> 7) * 32;
#pragma unroll 4
        for (int jj = 0; jj < 32; jj += 2) {
            int j = j0 + jj;
            float v0 = Atf[j * 128 + m];
            float v1 = Atf[(j + 1) * 128 + m];
            __half h0 = __float2half(v0), h1 = __float2half(v1);
            __half l0 = __float2half(v0 - __half2float(h0));
            __half l1 = __float2half(v1 - __half2float(h1));
            *(unsigned*)&Ah[m * 72 + j] = (unsigned)__half_as_ushort(h0) | ((unsigned)__half_as_ushort(h1) << 16);
            *(unsigned*)&Al[m * 72 + j] = (unsigned)__half_as_ushort(l0) | ((unsigned)__half_as_ushort(l1) << 16);
        }
    }
    __syncthreads();

    // exact fp32 zn chain (j ascending) from Atf (still intact until first B-stage)
    if (t < 128) {
        float s = 0.f;
        for (int j = 0; j < 64; ++j) { float a = Atf[j * 128 + t]; s = fmaf(a, a, s); }
        znl[t] = s;
    }

    const int w    = t >> 6;        // wave 0..3 -> rows [32w, 32w+32)
    const int lane = t & 63;
    const int c    = lane & 15;     // col within 16-tile
    const int q    = lane >> 4;     // k-quad / row-quad

    // A fragments, loaded once: [group g][K-step s]
    v8h Afh[2][2], Afl[2][2];
#pragma unroll
    for (int g = 0; g < 2; ++g) {
        int m = 32 * w + 16 * g + c;
#pragma unroll
        for (int s = 0; s < 2; ++s) {
            Afh[g][s] = *(const v8h*)&Ah[m * 72 + s * 32 + q * 8];
            Afl[g][s] = *(const v8h*)&Al[m * 72 + s * 32 + q * 8];
        }
    }

    float m1v[2][4], m2v[2][4]; int m1i[2][4];
#pragma unroll
    for (int g = 0; g < 2; ++g)
#pragma unroll
        for (int r = 0; r < 4; ++r) { m1v[g][r] = 3.4e38f; m2v[g][r] = 3.4e38f; m1i[g][r] = 0; }

    for (int kt = 0; kt < 8; ++kt) {
        __syncthreads();                      // zn/frag reads done; Bs reusable
        // stage 128 codes (hi+lo) from global fp16 arrays (L2-hot)
#pragma unroll
        for (int s2 = 0; s2 < 4; ++s2) {
            int idx = t + s2 * 256;               // 0..1023
            int code = idx >> 3;
            int off  = (idx & 7) * 8;
            size_t gsrc = ((size_t)(kt * 128 + code)) * 64 + off;
            *(uint4*)&Bh[code * 72 + off] = *(const uint4*)(cbh + gsrc);
            *(uint4*)&Bl[code * 72 + off] = *(const uint4*)(cbl + gsrc);
        }
        __syncthreads();

#pragma unroll
        for (int sub = 0; sub < 8; ++sub) {
            const int cl = sub * 16 + c;
            v8h Bfh0 = *(const v8h*)&Bh[cl * 72 + q * 8];
            v8h Bfh1 = *(const v8h*)&Bh[cl * 72 + 32 + q * 8];
            v8h Bfl0 = *(const v8h*)&Bl[cl * 72 + q * 8];
            v8h Bfl1 = *(const v8h*)&Bl[cl * 72 + 32 + q * 8];
            float cnc = cn_lds[kt * 128 + cl];
            const int kg = kt * 128 + cl;
#pragma unroll
            for (int g = 0; g < 2; ++g) {
                v4f acc = {0.f, 0.f, 0.f, 0.f};
                acc = __builtin_amdgcn_mfma_f32_16x16x32_f16(Afh[g][0], Bfh0, acc, 0, 0, 0);
                acc = __builtin_amdgcn_mfma_f32_16x16x32_f16(Afh[g][1], Bfh1, acc, 0, 0, 0);
                acc = __builtin_amdgcn_mfma_f32_16x16x32_f16(Afh[g][0], Bfl0, acc, 0, 0, 0);
                acc = __builtin_amdgcn_mfma_f32_16x16x32_f16(Afh[g][1], Bfl1, acc, 0, 0, 0);
                acc = __builtin_amdgcn_mfma_f32_16x16x32_f16(Afl[g][0], Bfh0, acc, 0, 0, 0);
                acc = __builtin_amdgcn_mfma_f32_16x16x32_f16(Afl[g][1], Bfh1, acc, 0, 0, 0);
#pragma unroll
                for (int r = 0; r < 4; ++r) {
                    float v = fmaf(-2.0f, acc[r], cnc);   // zn omitted: per-row constant
                    bool better = v < m1v[g][r];          // strict: kg ascending keeps first
                    m2v[g][r] = better ? m1v[g][r] : fminf(m2v[g][r], v);
                    m1i[g][r] = better ? kg : m1i[g][r];
                    m1v[g][r] = better ? v : m1v[g][r];
                }
            }
        }
    }

    // ---- top-2 merge across the 16 lanes holding each row ----
#pragma unroll
    for (int g = 0; g < 2; ++g)
#pragma unroll
        for (int r = 0; r < 4; ++r) {
            float a = m1v[g][r], b2 = m2v[g][r]; int ii = m1i[g][r];
#pragma unroll
            for (int mask = 1; mask <= 8; mask <<= 1) {
                float ov = __shfl_xor(a, mask, 64);
                int   oi = __shfl_xor(ii, mask, 64);
                float o2 = __shfl_xor(b2, mask, 64);
                bool take = (ov < a) || (ov == a && oi < ii);
                float loser = take ? a : ov;
                b2 = fminf(fminf(b2, o2), loser);
                a  = take ? ov : a;
                ii = take ? oi : ii;
            }
            if (c == 0) {
                int row = 32 * w + 16 * g + q * 4 + r;
                idx_lds[row] = ii;
                if ((b2 - a) < MARGIN) { int p = atomicAdd(&nflag, 1); flagrows[p] = row; }
            }
        }
    __syncthreads();

    // export flags for k_fix (no global atomics; per-block slots)
    int nf = nflag; if (nf > MAXFLG) nf = MAXFLG;
    if (t == 0) flg_cnt[blockIdx.x] = nf;
    if (t < nf) flg_list[blockIdx.x * MAXFLG + t] = flagrows[t];

    if (t < 128) {
        int bi = idx_lds[t];
        out[O_IDX + n0 + t] = (float)bi;      // provisional for flagged rows; k_fix overwrites
        idx_ws[n0 + t] = bi;
    }
}

// Exact fp32 re-argmin for flagged rows only. Grid = 512 (one per argmin block).
__global__ __launch_bounds__(256) void k_fix(const float* __restrict__ z_e,
                                             const float* __restrict__ cb,
                                             const float* __restrict__ cnorm,
                                             const int* __restrict__ flg_cnt,
                                             const int* __restrict__ flg_list,
                                             int* __restrict__ idx_ws,
                                             float* __restrict__ out) {
    const int blk = blockIdx.x;
    const int nf = flg_cnt[blk];
    if (nf == 0) return;
    __shared__ float redv4[4];
    __shared__ int   redi4[4];
    const int t = threadIdx.x;
    const int lane = t & 63, w = t >> 6;
    const int n0 = blk * 128;
    const int b   = n0 >> 12;
    const int hw0 = n0 & 4095;

    for (int f = 0; f < nf; ++f) {
        int row = flg_list[blk * MAXFLG + f];
        const float* zrow = z_e + (size_t)b * (DD * HW) + hw0 + row;
        // exact zn chain (same expression/order as reference path)
        float znr = 0.f;
        for (int j = 0; j < 64; ++j) { float v = zrow[(size_t)j * HW]; znr = fmaf(v, v, znr); }
        float best = 3.4e38f; int bi = 0;
#pragma unroll
        for (int c2 = 0; c2 < 4; ++c2) {
            int k = t * 4 + c2;                      // ascending within thread
            const float* ck = cb + (size_t)k * DD;
            float acc = 0.f;
            for (int j = 0; j < 64; ++j) acc = fmaf(zrow[(size_t)j * HW], ck[j], acc);
            float v = (znr - 2.0f * acc) + cnorm[k];
            if (v < best) { best = v; bi = k; }
        }
#pragma unroll
        for (int mask = 1; mask <= 32; mask <<= 1) {
            float ov = __shfl_xor(best, mask, 64);
            int   oi = __shfl_xor(bi, mask, 64);
            if (ov < best || (ov == best && oi < bi)) { best = ov; bi = oi; }
        }
        if (lane == 0) { redv4[w] = best; redi4[w] = bi; }
        __syncthreads();
        if (t == 0) {
            float bv = redv4[0]; int bix = redi4[0];
#pragma unroll
            for (int w2 = 1; w2 < 4; ++w2)
                if (redv4[w2] < bv || (redv4[w2] == bv && redi4[w2] < bix)) { bv = redv4[w2]; bix = redi4[w2]; }
            idx_ws[n0 + row] = bix;
            out[O_IDX + n0 + row] = (float)bix;
        }
        __syncthreads();
    }
}

// Fused output pass: 256 blocks (j, chunk c). Reads z once: e_k_ste + segment sums
// + histogram (j==0) + L_commit partials. cb column j staged in LDS.
__global__ __launch_bounds__(1024) void k_out(const int* __restrict__ idx_ws,
                                              const float* __restrict__ z_e,
                                              const float* __restrict__ cb,
                                              float* __restrict__ psum,
                                              int* __restrict__ pcnt,
                                              float* __restrict__ lc_part,
                                              float* __restrict__ out) {
    __shared__ float acc[KC];
    __shared__ int bins[KC];
    __shared__ float cbj[KC];
    __shared__ float lcr[16];
    const int j = blockIdx.x & 63;
    const int c = blockIdx.x >> 6;
    const int t = threadIdx.x;
    acc[t] = 0.f;
    bins[t] = 0;
    cbj[t] = cb[(size_t)t * DD + j];   // codebook column j (once per block)
    __syncthreads();
    const float* zj = z_e + (size_t)j * HW;
    float* oj = out + O_EK + (size_t)j * HW;
    const int base = c * 16384;
    float lc = 0.f;
#pragma unroll
    for (int i = 0; i < 4; ++i) {
        int n4 = base + i * 4096 + t * 4;
        int b = n4 >> 12, hw = n4 & 4095;
        size_t zoff = (size_t)b * (DD * HW) + hw;
        float4 z4 = *(const float4*)(zj + zoff);
        int4   k4 = *(const int4*)(idx_ws + n4);
        float e0 = cbj[k4.x], e1 = cbj[k4.y], e2 = cbj[k4.z], e3 = cbj[k4.w];
        float4 o4 = { z4.x + (e0 - z4.x), z4.y + (e1 - z4.y),
                      z4.z + (e2 - z4.z), z4.w + (e3 - z4.w) };
        *(float4*)(oj + zoff) = o4;                       // coalesced
        float d0 = z4.x - e0, d1 = z4.y - e1, d2 = z4.z - e2, d3 = z4.w - e3;
        lc = fmaf(d0, d0, lc); lc = fmaf(d1, d1, lc);
        lc = fmaf(d2, d2, lc); lc = fmaf(d3, d3, lc);
        atomicAdd(&acc[k4.x], z4.x);
        atomicAdd(&acc[k4.y], z4.y);
        atomicAdd(&acc[k4.z], z4.z);
        atomicAdd(&acc[k4.w], z4.w);
        if (j == 0) {
            atomicAdd(&bins[k4.x], 1); atomicAdd(&bins[k4.y], 1);
            atomicAdd(&bins[k4.z], 1); atomicAdd(&bins[k4.w], 1);
        }
    }
    __syncthreads();
    psum[(size_t)c * 65536 + j * 1024 + t] = acc[t];
    if (j == 0) pcnt[c * 1024 + t] = bins[t];
#pragma unroll
    for (int m = 32; m >= 1; m >>= 1) lc += __shfl_xor(lc, m, 64);
    if ((t & 63) == 0) lcr[t >> 6] = lc;
    __syncthreads();
    if (t == 0) {
        float s = 0.f;
#pragma unroll
        for (int u = 0; u < 16; ++u) s += lcr[u];
        lc_part[blockIdx.x] = s;
    }
}

// Fused epilogue, coalesced on outputs: e = k*64+j. 64 blocks x 1024.
__global__ __launch_bounds__(1024) void k_epi(const float* __restrict__ psum,
                                              const int* __restrict__ pcnt,
                                              const float* __restrict__ ema_sum,
                                              const float* __restrict__ ema_count,
                                              const float* __restrict__ n_ws,
                                              const float* __restrict__ lc_part,
                                              float* __restrict__ out) {
    const int t = threadIdx.x;
    const int e = blockIdx.x * 1024 + t;
    const int k = e >> 6, j = e & 63;
    float s4 = psum[j * 1024 + k] + psum[65536 + j * 1024 + k]
             + psum[131072 + j * 1024 + k] + psum[196608 + j * 1024 + k];
    float ns = ema_sum[e] * 0.99f + 0.01f * s4;
    out[O_SUM + e] = ns;
    int cnt = pcnt[k] + pcnt[1024 + k] + pcnt[2048 + k] + pcnt[3072 + k];
    float nc = ema_count[k] * 0.99f + 0.01f * (float)cnt;
    float n  = n_ws[0];
    float cs = (nc + 1e-5f) / (n + 1024.0f * 1e-5f) * n;
    out[O_CB + e] = ns / cs;
    if (blockIdx.x == 0) {
        int c2 = pcnt[t] + pcnt[1024 + t] + pcnt[2048 + t] + pcnt[3072 + t];
        out[O_CNT + t] = ema_count[t] * 0.99f + 0.01f * (float)c2;
    }
    if (blockIdx.x == 1) {
        __shared__ float red[512];
        if (t < 512) red[t] = (t < 256) ? lc_part[t] : 0.f;
        __syncthreads();
        for (int s = 256; s >= 1; s >>= 1) {
            if (t < s) red[t] += red[t + s];
            __syncthreads();
        }
        if (t == 0) out[O_L] = 1.25f * red[0] * (1.0f / 4194304.0f);
    }
}

extern "C" void kernel_launch(void* const* d_in, const int* in_sizes, int n_in,
                              void* d_out, int out_size, void* d_ws, size_t ws_size,
                              hipStream_t stream) {
    const float* z_e       = (const float*)d_in[0];
    const float* cb        = (const float*)d_in[1];
    const float* ema_count = (const float*)d_in[2];
    const float* ema_sum   = (const float*)d_in[3];
    float* out             = (float*)d_out;

    float* ws_f      = (float*)d_ws;
    int*   idx_ws    = (int*)d_ws;
    float* lc_part   = ws_f + WS_LCPART;
    float* n_ws      = ws_f + WS_N;
    float* cnorm_ws  = ws_f + WS_CNORM;
    float* psum      = ws_f + WS_PSUM;
    int*   pcnt      = (int*)(ws_f + WS_PCNT);
    int*   flg_cnt   = (int*)(ws_f + WS_FLGC);
    int*   flg_list  = (int*)(ws_f + WS_FLGL);
    unsigned short* cbh = (unsigned short*)(ws_f + WS_CBH);
    unsigned short* cbl = (unsigned short*)(ws_f + WS_CBL);

    k_pre<<<256, 256, 0, stream>>>(cb, ema_count, cnorm_ws, n_ws, cbh, cbl);
    k_argmin<<<NTOT / 128, 256, 0, stream>>>(z_e, cbh, cbl, cnorm_ws, idx_ws, flg_cnt, flg_list, out);
    k_fix<<<NTOT / 128, 256, 0, stream>>>(z_e, cb, cnorm_ws, flg_cnt, flg_list, idx_ws, out);
    k_out<<<256, 1024, 0, stream>>>(idx_ws, z_e, cb, psum, pcnt, lc_part, out);
    k_epi<<<64, 1024, 0, stream>>>(psum, pcnt, ema_sum, ema_count, n_ws, lc_part, out);
}